// Round 4
// baseline (65.525 us; speedup 1.0000x reference)
//
#include <hip/hip_runtime.h>

typedef __attribute__((ext_vector_type(8))) short short8;
typedef __attribute__((ext_vector_type(4))) short short4v;
typedef __attribute__((ext_vector_type(4))) float f32x4;
typedef __attribute__((ext_vector_type(4))) unsigned int uint4v;
typedef __attribute__((ext_vector_type(2))) unsigned int uint2v;
typedef unsigned short us;
typedef unsigned int u32;

#define NB 4
#define NC 64
#define NN 4096
#define ND 64
#define LOG2E 1.44269504088896340736f

static __device__ __forceinline__ us f2bf(float x) {
    u32 u = __builtin_bit_cast(u32, x);
    u += 0x7FFFu + ((u >> 16) & 1u);
    return (us)(u >> 16);
}

static __device__ __forceinline__ u32 cvtpk(float a, float b) {
    u32 r;
    asm("v_cvt_pk_bf16_f32 %0, %1, %2" : "=v"(r) : "v"(a), "v"(b));
    return r;
}

static __device__ __forceinline__ short8 comb(short4v a, short4v b) {
    short8 r;
    r[0] = a[0]; r[1] = a[1]; r[2] = a[2]; r[3] = a[3];
    r[4] = b[0]; r[5] = b[1]; r[6] = b[2]; r[7] = b[3];
    return r;
}

static __device__ __forceinline__ void async_copy16(void* lds, const void* g) {
    __builtin_amdgcn_global_load_lds(
        (const __attribute__((address_space(1))) u32*)g,
        (__attribute__((address_space(3))) u32*)lds, 16, 0, 0);
}

// ---------------- kernel 1: Wo -> bf16 ----------------
__global__ void cvt_wo_kernel(const float* __restrict__ Wo, us* __restrict__ Wob) {
    int i = blockIdx.x * 256 + threadIdx.x;
    if (i < ND * (ND + NC)) Wob[i] = f2bf(Wo[i]);
}

// ---------------- kernel 2: projections via MFMA (role-split) ----------------
__global__ __launch_bounds__(256) void proj_kernel(
    const float* __restrict__ x,
    const float* __restrict__ Wq, const float* __restrict__ bq,
    const float* __restrict__ Wk, const float* __restrict__ bk,
    const float* __restrict__ Wv, const float* __restrict__ bv,
    us* __restrict__ Qt, us* __restrict__ Kt,
    us* __restrict__ Vm, us* __restrict__ Xbt)
{
    __shared__ float xs[64][64];                 // [c][n] fp32
    __shared__ __align__(16) us xT[64][64];      // [n][c] bf16, XOR-swizzled
    const int t = threadIdx.x;
    const int bid = blockIdx.x;
    const int role = bid & 1;
    const int v = bid >> 1;
    const int b = v >> 6;
    const int n0 = (v & 63) << 6;
    const float* xb = x + (size_t)b * NC * NN + n0;
    #pragma unroll
    for (int i = 0; i < 4; ++i) {
        int s = t + i * 256;
        int c = s >> 4, col = (s & 15) << 2;
        *(f32x4*)&xs[c][col] = *(const f32x4*)&xb[(size_t)c * NN + col];
    }
    __syncthreads();
    {
        int n = t & 63, cg = t >> 6;
        int c0 = cg << 4;
        u32 pk[8];
        #pragma unroll
        for (int j = 0; j < 8; ++j) {
            float a0 = xs[c0 + 2 * j][n], a1 = xs[c0 + 2 * j + 1][n];
            pk[j] = (u32)f2bf(a0) | ((u32)f2bf(a1) << 16);
        }
        int b0 = (cg * 2) ^ (n & 7), b1 = (cg * 2 + 1) ^ (n & 7);
        *(uint4v*)&xT[n][b0 * 8] = (uint4v){pk[0], pk[1], pk[2], pk[3]};
        *(uint4v*)&xT[n][b1 * 8] = (uint4v){pk[4], pk[5], pk[6], pk[7]};
        if (role == 1) {
            us* dst = Xbt + (size_t)(b * NN + n0 + n) * ND + c0;
            *(uint4v*)dst       = (uint4v){pk[0], pk[1], pk[2], pk[3]};
            *(uint4v*)(dst + 8) = (uint4v){pk[4], pk[5], pk[6], pk[7]};
        }
    }
    __syncthreads();
    const int w = t >> 6, l = t & 63, h = l >> 4, ln = l & 15;
    const int row = w * 16 + ln;
    short8 xq0 = *(const short8*)&xT[row][((h ^ (row & 7)) << 3)];
    short8 xq1 = *(const short8*)&xT[row][(((4 + h) ^ (row & 7)) << 3)];

    if (role == 0) {
        #pragma unroll
        for (int p = 0; p < 2; ++p) {
            const float* W = p ? Wk : Wq;
            const float* bias = p ? bk : bq;
            const float sc = p ? 1.0f : LOG2E;
            us* outp = p ? Kt : Qt;
            #pragma unroll
            for (int di = 0; di < 4; ++di) {
                const int d = di * 16 + ln;
                const float* wr = W + d * 64;
                short8 a0, a1;
                f32x4 f0 = *(const f32x4*)(wr + h * 8);
                f32x4 f1 = *(const f32x4*)(wr + h * 8 + 4);
                f32x4 f2 = *(const f32x4*)(wr + 32 + h * 8);
                f32x4 f3 = *(const f32x4*)(wr + 32 + h * 8 + 4);
                #pragma unroll
                for (int j = 0; j < 4; ++j) {
                    a0[j] = (short)f2bf(f0[j] * sc); a0[4 + j] = (short)f2bf(f1[j] * sc);
                    a1[j] = (short)f2bf(f2[j] * sc); a1[4 + j] = (short)f2bf(f3[j] * sc);
                }
                f32x4 acc = *(const f32x4*)(bias + di * 16 + h * 4);
                acc *= sc;
                acc = __builtin_amdgcn_mfma_f32_16x16x32_bf16(a0, xq0, acc, 0, 0, 0);
                acc = __builtin_amdgcn_mfma_f32_16x16x32_bf16(a1, xq1, acc, 0, 0, 0);
                u32 lo = (u32)f2bf(acc[0]) | ((u32)f2bf(acc[1]) << 16);
                u32 hi = (u32)f2bf(acc[2]) | ((u32)f2bf(acc[3]) << 16);
                *(uint2v*)(outp + (size_t)(b * NN + n0 + row) * ND + di * 16 + h * 4) = (uint2v){lo, hi};
            }
        }
    } else {
        #pragma unroll
        for (int di = 0; di < 4; ++di) {
            const int d = di * 16 + ln;
            const float* wr = Wv + d * 64;
            short8 a0, a1;
            f32x4 f0 = *(const f32x4*)(wr + h * 8);
            f32x4 f1 = *(const f32x4*)(wr + h * 8 + 4);
            f32x4 f2 = *(const f32x4*)(wr + 32 + h * 8);
            f32x4 f3 = *(const f32x4*)(wr + 32 + h * 8 + 4);
            #pragma unroll
            for (int j = 0; j < 4; ++j) {
                a0[j] = (short)f2bf(f0[j]); a0[4 + j] = (short)f2bf(f1[j]);
                a1[j] = (short)f2bf(f2[j]); a1[4 + j] = (short)f2bf(f3[j]);
            }
            f32x4 acc = *(const f32x4*)(bv + di * 16 + h * 4);
            acc = __builtin_amdgcn_mfma_f32_16x16x32_bf16(a0, xq0, acc, 0, 0, 0);
            acc = __builtin_amdgcn_mfma_f32_16x16x32_bf16(a1, xq1, acc, 0, 0, 0);
            us* vp = Vm + (size_t)(b * ND + di * 16 + h * 4) * NN + n0 + row;
            vp[0] = f2bf(acc[0]); vp[NN] = f2bf(acc[1]);
            vp[2 * NN] = f2bf(acc[2]); vp[3 * NN] = f2bf(acc[3]);
        }
    }
}

// ---------------- kernel 3: flash attention + fused output conv ----------------
static __device__ __forceinline__ void mask_bounds(int pt, int n016, int ng,
    int& lo_n, int& hi_n, int& lo_min, int& lo_max, int& hi_min, int& hi_max)
{
    if (pt == 0)      { lo_n = 0;           hi_n = ng;          lo_min = 0;              lo_max = 0;             hi_min = n016;           hi_max = n016 + 15; }
    else if (pt == 1) { lo_n = NN - 1 - ng; hi_n = NN - 1;      lo_min = NN - 16 - n016; lo_max = NN - 1 - n016; hi_min = NN - 1;         hi_max = NN - 1; }
    else if (pt == 2) { lo_n = ng;          hi_n = NN - 1;      lo_min = n016;           lo_max = n016 + 15;     hi_min = NN - 1;         hi_max = NN - 1; }
    else if (pt == 3) { lo_n = 0;           hi_n = NN - 1 - ng; lo_min = 0;              lo_max = 0;             hi_min = NN - 16 - n016; hi_max = NN - 1 - n016; }
    else              { lo_n = 0;           hi_n = NN - 1;      lo_min = 0;              lo_max = 0;             hi_min = NN - 1;         hi_max = NN - 1; }
}

__global__ __launch_bounds__(256) void attn_kernel(
    const us* __restrict__ Qt, const us* __restrict__ Kt,
    const us* __restrict__ Vm, const us* __restrict__ Xbt,
    const us* __restrict__ Wob, const float* __restrict__ bo,
    const int* __restrict__ ordp, float* __restrict__ out)
{
    // LDS: [m-stream][dbuf] 64x64 bf16 tiles, XOR-swizzled (16B blk ^ (row&7)); 64KB
    __shared__ __align__(16) us Kl[2][2][64 * 64];
    __shared__ __align__(16) us Vl[2][2][64 * 64];

    const int tid = threadIdx.x;
    const int w = tid >> 6, l = tid & 63, h = l >> 4, ln = l & 15;
    const int nh = w & 1, mh = w >> 1;            // 2x2: n-split-2 (16q), m-split-2
    const int bid = blockIdx.x;
    const int vid = (bid & 7) * 64 + (bid >> 3);  // bijective XCD swizzle (512 = 8*64)
    const int b = vid >> 7;
    const int n0 = (vid & 127) << 5;              // 32-q tile
    const int n016 = n0 + nh * 16;
    const int ng = n016 + ln;

    const int ord = ordp[0];
    int pt = 4;
    if (ord == 1) pt = 0;
    else if (ord == 2 || ord == 3) pt = 1;
    else if (ord == 4 || ord == 5 || ord == 8) pt = 2;
    else if (ord == 6 || ord == 7) pt = 3;
    int lo_n, hi_n, lo_min, lo_max, hi_min, hi_max;
    mask_bounds(pt, n016, ng, lo_n, hi_n, lo_min, lo_max, hi_min, hi_max);

    const us* kb = Kt + (size_t)b * NN * ND;
    const us* vb = Vm + (size_t)b * ND * NN;
    const us* qrow = Qt + (size_t)(b * NN + n016 + ln) * ND;
    short8 q0 = *(const short8*)(qrow + h * 8);
    short8 q1 = *(const short8*)(qrow + 32 + h * 8);

    f32x4 O[4];
    #pragma unroll
    for (int d = 0; d < 4; ++d) O[d] = (f32x4){0.f, 0.f, 0.f, 0.f};
    float Lp = 0.f;

    // staging role: wave w -> stream sw = w>>1, type K/V = w&1; 8KB (8 calls)/wave/iter
    const int sw = w >> 1, typ = w & 1;
    auto stage = [&](int buf, int t) {
        const int m_base = sw * 2048 + t * 64;
        #pragma unroll
        for (int r = 0; r < 8; ++r) {
            const int rl = r * 8 + (l >> 3);
            const int blk = l & 7;
            if (typ == 0) {
                const us* src = kb + (size_t)(m_base + rl) * ND + ((blk ^ (rl & 7)) << 3);
                async_copy16(&Kl[sw][buf][r * 8 * 64], src);
            } else {
                const us* src = vb + (size_t)rl * NN + m_base + ((blk ^ (rl & 7)) << 3);
                async_copy16(&Vl[sw][buf][r * 8 * 64], src);
            }
        }
    };

    stage(0, 0);
    for (int t = 0; t < 32; ++t) {
        if (t < 31) {
            stage((t + 1) & 1, t + 1);
            asm volatile("s_waitcnt vmcnt(8)" ::: "memory");
        } else {
            asm volatile("s_waitcnt vmcnt(0)" ::: "memory");
        }
        __builtin_amdgcn_s_barrier();
        __builtin_amdgcn_sched_barrier(0);   // fence: nothing crosses into/out of compute

        const us* KT = Kl[mh][t & 1];
        const us* VT = Vl[mh][t & 1];
        const int m0 = mh * 2048 + t * 64;

        __builtin_amdgcn_s_setprio(1);
        float p[16];
        #pragma unroll
        for (int mss = 0; mss < 4; ++mss) {
            const int row = mss * 16 + ln;
            short8 k0 = *(const short8*)&KT[row * 64 + ((h ^ (row & 7)) << 3)];
            short8 k1 = *(const short8*)&KT[row * 64 + (((4 + h) ^ (row & 7)) << 3)];
            f32x4 st = {0.f, 0.f, 0.f, 0.f};
            st = __builtin_amdgcn_mfma_f32_16x16x32_bf16(k0, q0, st, 0, 0, 0);
            st = __builtin_amdgcn_mfma_f32_16x16x32_bf16(k1, q1, st, 0, 0, 0);
            #pragma unroll
            for (int r = 0; r < 4; ++r) {
                float pv = __builtin_amdgcn_exp2f(st[r]);  // no max-subtraction: |logit| small
                p[mss * 4 + r] = pv;
                Lp += pv;
            }
        }
        const bool skip = (m0 + 63 < lo_min) || (m0 > hi_max);
        if (!skip) {
            const bool full = (m0 >= lo_max) && (m0 + 63 <= hi_min);
            if (!full) {
                #pragma unroll
                for (int mss = 0; mss < 4; ++mss)
                    #pragma unroll
                    for (int r = 0; r < 4; ++r) {
                        const int mg = m0 + mss * 16 + h * 4 + r;
                        if (mg < lo_n || mg > hi_n) p[mss * 4 + r] = 0.f;
                    }
            }
            #pragma unroll
            for (int ks = 0; ks < 2; ++ks) {
                uint4v pw;
                pw[0] = cvtpk(p[ks * 8 + 0], p[ks * 8 + 1]);
                pw[1] = cvtpk(p[ks * 8 + 2], p[ks * 8 + 3]);
                pw[2] = cvtpk(p[ks * 8 + 4], p[ks * 8 + 5]);
                pw[3] = cvtpk(p[ks * 8 + 6], p[ks * 8 + 7]);
                short8 pb = __builtin_bit_cast(short8, pw);
                #pragma unroll
                for (int ds = 0; ds < 4; ++ds) {
                    const int rowv = ds * 16 + ln;
                    const int b1 = ks * 4 + (h >> 1);
                    short4v va  = *(const short4v*)&VT[rowv * 64 + ((b1 ^ (rowv & 7)) << 3) + (h & 1) * 4];
                    short4v vb2 = *(const short4v*)&VT[rowv * 64 + (((b1 + 2) ^ (rowv & 7)) << 3) + (h & 1) * 4];
                    O[ds] = __builtin_amdgcn_mfma_f32_16x16x32_bf16(comb(va, vb2), pb, O[ds], 0, 0, 0);
                }
            }
        }
        __builtin_amdgcn_s_setprio(0);
        __builtin_amdgcn_sched_barrier(0);   // fence: no sinking past the barrier
        __builtin_amdgcn_s_barrier();
    }

    // ---- in-block combine across mh (L additive; no max-tracking) ----
    float Lw = Lp;
    Lw += __shfl_xor(Lw, 16);
    Lw += __shfl_xor(Lw, 32);

    float* cO = (float*)&Kl[0][0][0];   // [nh][16 cols][64 rows] fp32, 8KB
    float* cL = (float*)&Vl[0][0][0];   // [nh][16]
    if (mh == 1) {
        #pragma unroll
        for (int ds = 0; ds < 4; ++ds)
            *(f32x4*)&cO[nh * 1024 + ln * 64 + ds * 16 + h * 4] = O[ds];
        if (l < 16) cL[nh * 16 + l] = Lw;
    }
    __syncthreads();
    if (mh == 1) return;

    const float gL = Lw + cL[nh * 16 + ln];
    const float rl2 = 1.0f / gL;
    #pragma unroll
    for (int ds = 0; ds < 4; ++ds) {
        f32x4 part = *(const f32x4*)&cO[nh * 1024 + ln * 64 + ds * 16 + h * 4];
        O[ds] = (O[ds] + part) * rl2;
    }

    // ---- fused epilogue: out = Wo . [o; x] + bo ----
    short8 ob0, ob1;
    #pragma unroll
    for (int r = 0; r < 4; ++r) {
        ob0[r]     = (short)f2bf(O[0][r]);
        ob0[4 + r] = (short)f2bf(O[1][r]);
        ob1[r]     = (short)f2bf(O[2][r]);
        ob1[4 + r] = (short)f2bf(O[3][r]);
    }
    const us* xrow = Xbt + (size_t)(b * NN + n016 + ln) * ND;
    short8 xb0 = comb(*(const short4v*)(xrow + h * 4),      *(const short4v*)(xrow + 16 + h * 4));
    short8 xb1 = comb(*(const short4v*)(xrow + 32 + h * 4), *(const short4v*)(xrow + 48 + h * 4));

    #pragma unroll
    for (int os = 0; os < 4; ++os) {
        const us* wrow = Wob + (size_t)(os * 16 + ln) * 128;
        short8 w0 = comb(*(const short4v*)(wrow + h * 4),       *(const short4v*)(wrow + 16 + h * 4));
        short8 w1 = comb(*(const short4v*)(wrow + 32 + h * 4),  *(const short4v*)(wrow + 48 + h * 4));
        short8 w2 = comb(*(const short4v*)(wrow + 64 + h * 4),  *(const short4v*)(wrow + 80 + h * 4));
        short8 w3 = comb(*(const short4v*)(wrow + 96 + h * 4),  *(const short4v*)(wrow + 112 + h * 4));
        f32x4 acc = *(const f32x4*)(bo + os * 16 + h * 4);
        acc = __builtin_amdgcn_mfma_f32_16x16x32_bf16(w0, ob0, acc, 0, 0, 0);
        acc = __builtin_amdgcn_mfma_f32_16x16x32_bf16(w1, ob1, acc, 0, 0, 0);
        acc = __builtin_amdgcn_mfma_f32_16x16x32_bf16(w2, xb0, acc, 0, 0, 0);
        acc = __builtin_amdgcn_mfma_f32_16x16x32_bf16(w3, xb1, acc, 0, 0, 0);
        #pragma unroll
        for (int r = 0; r < 4; ++r)
            out[((size_t)b * ND + os * 16 + h * 4 + r) * NN + n016 + ln] = acc[r];
    }
}

extern "C" void kernel_launch(void* const* d_in, const int* in_sizes, int n_in,
                              void* d_out, int out_size, void* d_ws, size_t ws_size,
                              hipStream_t stream) {
    (void)in_sizes; (void)n_in; (void)out_size; (void)ws_size;
    const float* x  = (const float*)d_in[0];
    const float* Wq = (const float*)d_in[1];
    const float* bq = (const float*)d_in[2];
    const float* Wk = (const float*)d_in[3];
    const float* bk = (const float*)d_in[4];
    const float* Wv = (const float*)d_in[5];
    const float* bv = (const float*)d_in[6];
    const float* Wo = (const float*)d_in[7];
    const float* bo = (const float*)d_in[8];
    const int* ord  = (const int*)d_in[9];
    float* out = (float*)d_out;

    // workspace: 4 x 2MB bf16 + 16KB = 8.02MB (round-2-proven footprint)
    us* Qt  = (us*)d_ws;
    us* Kt  = Qt  + (size_t)NB * NN * ND;
    us* Vm  = Kt  + (size_t)NB * NN * ND;
    us* Xbt = Vm  + (size_t)NB * NN * ND;
    us* Wob = Xbt + (size_t)NB * NN * ND;

    cvt_wo_kernel<<<dim3(32), dim3(256), 0, stream>>>(Wo, Wob);
    proj_kernel<<<dim3(NB * 64 * 2), dim3(256), 0, stream>>>(
        x, Wq, bq, Wk, bk, Wv, bv, Qt, Kt, Vm, Xbt);
    attn_kernel<<<dim3(512), dim3(256), 0, stream>>>(
        Qt, Kt, Vm, Xbt, Wob, bo, ord, out);
}

// Round 5
// 57.195 us; speedup vs baseline: 1.1457x; 1.1457x over previous
//
#include <hip/hip_runtime.h>

typedef __attribute__((ext_vector_type(8))) short short8;
typedef __attribute__((ext_vector_type(4))) short short4v;
typedef __attribute__((ext_vector_type(4))) float f32x4;
typedef __attribute__((ext_vector_type(16))) float f32x16;
typedef __attribute__((ext_vector_type(4))) unsigned int uint4v;
typedef __attribute__((ext_vector_type(2))) unsigned int uint2v;
typedef unsigned short us;
typedef unsigned int u32;

#define NB 4
#define NC 64
#define NN 4096
#define ND 64
#define LOG2E 1.44269504088896340736f

static __device__ __forceinline__ us f2bf(float x) {
    u32 u = __builtin_bit_cast(u32, x);
    u += 0x7FFFu + ((u >> 16) & 1u);
    return (us)(u >> 16);
}

static __device__ __forceinline__ u32 cvtpk(float a, float b) {
    u32 r;
    asm("v_cvt_pk_bf16_f32 %0, %1, %2" : "=v"(r) : "v"(a), "v"(b));
    return r;
}

static __device__ __forceinline__ short8 comb(short4v a, short4v b) {
    short8 r;
    r[0] = a[0]; r[1] = a[1]; r[2] = a[2]; r[3] = a[3];
    r[4] = b[0]; r[5] = b[1]; r[6] = b[2]; r[7] = b[3];
    return r;
}

static __device__ __forceinline__ void async_copy16(void* lds, const void* g) {
    __builtin_amdgcn_global_load_lds(
        (const __attribute__((address_space(1))) u32*)g,
        (__attribute__((address_space(3))) u32*)lds, 16, 0, 0);
}

// ---------------- kernel 1: Wo -> bf16 ----------------
__global__ void cvt_wo_kernel(const float* __restrict__ Wo, us* __restrict__ Wob) {
    int i = blockIdx.x * 256 + threadIdx.x;
    if (i < ND * (ND + NC)) Wob[i] = f2bf(Wo[i]);
}

// ---------------- kernel 2: projections via MFMA (role-split) ----------------
__global__ __launch_bounds__(256) void proj_kernel(
    const float* __restrict__ x,
    const float* __restrict__ Wq, const float* __restrict__ bq,
    const float* __restrict__ Wk, const float* __restrict__ bk,
    const float* __restrict__ Wv, const float* __restrict__ bv,
    us* __restrict__ Qt, us* __restrict__ Kt,
    us* __restrict__ Vm, us* __restrict__ Xbt)
{
    __shared__ float xs[64][64];                 // [c][n] fp32
    __shared__ __align__(16) us xT[64][64];      // [n][c] bf16, XOR-swizzled
    const int t = threadIdx.x;
    const int bid = blockIdx.x;
    const int role = bid & 1;
    const int v = bid >> 1;
    const int b = v >> 6;
    const int n0 = (v & 63) << 6;
    const float* xb = x + (size_t)b * NC * NN + n0;
    #pragma unroll
    for (int i = 0; i < 4; ++i) {
        int s = t + i * 256;
        int c = s >> 4, col = (s & 15) << 2;
        *(f32x4*)&xs[c][col] = *(const f32x4*)&xb[(size_t)c * NN + col];
    }
    __syncthreads();
    {
        int n = t & 63, cg = t >> 6;
        int c0 = cg << 4;
        u32 pk[8];
        #pragma unroll
        for (int j = 0; j < 8; ++j) {
            float a0 = xs[c0 + 2 * j][n], a1 = xs[c0 + 2 * j + 1][n];
            pk[j] = (u32)f2bf(a0) | ((u32)f2bf(a1) << 16);
        }
        int b0 = (cg * 2) ^ (n & 7), b1 = (cg * 2 + 1) ^ (n & 7);
        *(uint4v*)&xT[n][b0 * 8] = (uint4v){pk[0], pk[1], pk[2], pk[3]};
        *(uint4v*)&xT[n][b1 * 8] = (uint4v){pk[4], pk[5], pk[6], pk[7]};
        if (role == 1) {
            us* dst = Xbt + (size_t)(b * NN + n0 + n) * ND + c0;
            *(uint4v*)dst       = (uint4v){pk[0], pk[1], pk[2], pk[3]};
            *(uint4v*)(dst + 8) = (uint4v){pk[4], pk[5], pk[6], pk[7]};
        }
    }
    __syncthreads();
    const int w = t >> 6, l = t & 63, h = l >> 4, ln = l & 15;
    const int row = w * 16 + ln;
    short8 xq0 = *(const short8*)&xT[row][((h ^ (row & 7)) << 3)];
    short8 xq1 = *(const short8*)&xT[row][(((4 + h) ^ (row & 7)) << 3)];

    if (role == 0) {
        #pragma unroll
        for (int p = 0; p < 2; ++p) {
            const float* W = p ? Wk : Wq;
            const float* bias = p ? bk : bq;
            const float sc = p ? 1.0f : LOG2E;
            us* outp = p ? Kt : Qt;
            #pragma unroll
            for (int di = 0; di < 4; ++di) {
                const int d = di * 16 + ln;
                const float* wr = W + d * 64;
                short8 a0, a1;
                f32x4 f0 = *(const f32x4*)(wr + h * 8);
                f32x4 f1 = *(const f32x4*)(wr + h * 8 + 4);
                f32x4 f2 = *(const f32x4*)(wr + 32 + h * 8);
                f32x4 f3 = *(const f32x4*)(wr + 32 + h * 8 + 4);
                #pragma unroll
                for (int j = 0; j < 4; ++j) {
                    a0[j] = (short)f2bf(f0[j] * sc); a0[4 + j] = (short)f2bf(f1[j] * sc);
                    a1[j] = (short)f2bf(f2[j] * sc); a1[4 + j] = (short)f2bf(f3[j] * sc);
                }
                f32x4 acc = *(const f32x4*)(bias + di * 16 + h * 4);
                acc *= sc;
                acc = __builtin_amdgcn_mfma_f32_16x16x32_bf16(a0, xq0, acc, 0, 0, 0);
                acc = __builtin_amdgcn_mfma_f32_16x16x32_bf16(a1, xq1, acc, 0, 0, 0);
                u32 lo = (u32)f2bf(acc[0]) | ((u32)f2bf(acc[1]) << 16);
                u32 hi = (u32)f2bf(acc[2]) | ((u32)f2bf(acc[3]) << 16);
                *(uint2v*)(outp + (size_t)(b * NN + n0 + row) * ND + di * 16 + h * 4) = (uint2v){lo, hi};
            }
        }
    } else {
        #pragma unroll
        for (int di = 0; di < 4; ++di) {
            const int d = di * 16 + ln;
            const float* wr = Wv + d * 64;
            short8 a0, a1;
            f32x4 f0 = *(const f32x4*)(wr + h * 8);
            f32x4 f1 = *(const f32x4*)(wr + h * 8 + 4);
            f32x4 f2 = *(const f32x4*)(wr + 32 + h * 8);
            f32x4 f3 = *(const f32x4*)(wr + 32 + h * 8 + 4);
            #pragma unroll
            for (int j = 0; j < 4; ++j) {
                a0[j] = (short)f2bf(f0[j]); a0[4 + j] = (short)f2bf(f1[j]);
                a1[j] = (short)f2bf(f2[j]); a1[4 + j] = (short)f2bf(f3[j]);
            }
            f32x4 acc = *(const f32x4*)(bv + di * 16 + h * 4);
            acc = __builtin_amdgcn_mfma_f32_16x16x32_bf16(a0, xq0, acc, 0, 0, 0);
            acc = __builtin_amdgcn_mfma_f32_16x16x32_bf16(a1, xq1, acc, 0, 0, 0);
            us* vp = Vm + (size_t)(b * ND + di * 16 + h * 4) * NN + n0 + row;
            vp[0] = f2bf(acc[0]); vp[NN] = f2bf(acc[1]);
            vp[2 * NN] = f2bf(acc[2]); vp[3 * NN] = f2bf(acc[3]);
        }
    }
}

// ---------------- kernel 3: flash attention (32x32 MFMA, 4-stream LDS) ----------------
static __device__ __forceinline__ void mask_bounds32(int pt, int n032, int ng,
    int& lo_n, int& hi_n, int& lo_min, int& lo_max, int& hi_min, int& hi_max)
{
    if (pt == 0)      { lo_n = 0;           hi_n = ng;          lo_min = 0;              lo_max = 0;             hi_min = n032;           hi_max = n032 + 31; }
    else if (pt == 1) { lo_n = NN - 1 - ng; hi_n = NN - 1;      lo_min = NN - 32 - n032; lo_max = NN - 1 - n032; hi_min = NN - 1;         hi_max = NN - 1; }
    else if (pt == 2) { lo_n = ng;          hi_n = NN - 1;      lo_min = n032;           lo_max = n032 + 31;     hi_min = NN - 1;         hi_max = NN - 1; }
    else if (pt == 3) { lo_n = 0;           hi_n = NN - 1 - ng; lo_min = 0;              lo_max = 0;             hi_min = NN - 32 - n032; hi_max = NN - 1 - n032; }
    else              { lo_n = 0;           hi_n = NN - 1;      lo_min = 0;              lo_max = 0;             hi_min = NN - 1;         hi_max = NN - 1; }
}

// dynamic LDS: K tiles [4 streams][2 bufs][64x64 us] = 64KB, then V same = 64KB
extern __shared__ __align__(16) us lds_us[];
#define KT_(s, bf) (lds_us + ((s) * 2 + (bf)) * 4096)
#define VT_(s, bf) (lds_us + 32768 + ((s) * 2 + (bf)) * 4096)

__global__ __launch_bounds__(512, 2) void attn_kernel(
    const us* __restrict__ Qt, const us* __restrict__ Kt,
    const us* __restrict__ Vm, const us* __restrict__ Xbt,
    const us* __restrict__ Wob, const float* __restrict__ bo,
    const int* __restrict__ ordp, float* __restrict__ out)
{
    const int tid = threadIdx.x;
    const int w = tid >> 6, l = tid & 63;
    const int hi = l >> 5, ln = l & 31;
    const int mh = w >> 1, nh = w & 1;            // 4 m-streams x 2 n-halves
    const int bid = blockIdx.x;
    const int vid = (bid & 7) * 32 + (bid >> 3);  // bijective XCD swizzle (256 = 8*32)
    const int b = vid >> 6;
    const int n0 = (vid & 63) << 6;               // 64-q block tile
    const int n032 = n0 + nh * 32;
    const int ng = n032 + ln;

    const int ord = ordp[0];
    int pt = 4;
    if (ord == 1) pt = 0;
    else if (ord == 2 || ord == 3) pt = 1;
    else if (ord == 4 || ord == 5 || ord == 8) pt = 2;
    else if (ord == 6 || ord == 7) pt = 3;
    int lo_n, hi_n, lo_min, lo_max, hi_min, hi_max;
    mask_bounds32(pt, n032, ng, lo_n, hi_n, lo_min, lo_max, hi_min, hi_max);

    const us* kb = Kt + (size_t)b * NN * ND;
    const us* vb = Vm + (size_t)b * ND * NN;
    const us* qrow = Qt + (size_t)(b * NN + n032 + ln) * ND;
    short8 qf0 = *(const short8*)(qrow + 0 * 16 + hi * 8);
    short8 qf1 = *(const short8*)(qrow + 1 * 16 + hi * 8);
    short8 qf2 = *(const short8*)(qrow + 2 * 16 + hi * 8);
    short8 qf3 = *(const short8*)(qrow + 3 * 16 + hi * 8);

    f32x16 O0, O1, Z;
    #pragma unroll
    for (int i = 0; i < 16; ++i) { O0[i] = 0.f; O1[i] = 0.f; Z[i] = 0.f; }
    float Lp = 0.f;

    // staging: wave (mh, nh) stages stream mh; nh==0 -> K, nh==1 -> V. 8KB (8 calls)/wave/iter
    auto stage = [&](int buf, int t) {
        const int m_base = mh * 1024 + t * 64;
        us* dstK = KT_(mh, buf);
        us* dstV = VT_(mh, buf);
        #pragma unroll
        for (int r = 0; r < 8; ++r) {
            const int rl = r * 8 + (l >> 3);
            const int blk = l & 7;
            if (nh == 0) {
                const us* src = kb + (size_t)(m_base + rl) * ND + ((blk ^ (rl & 7)) << 3);
                async_copy16(dstK + r * 8 * 64, src);
            } else {
                const us* src = vb + (size_t)rl * NN + m_base + ((blk ^ (rl & 7)) << 3);
                async_copy16(dstV + r * 8 * 64, src);
            }
        }
    };

    stage(0, 0);
    for (int t = 0; t < 16; ++t) {
        if (t < 15) {
            stage((t + 1) & 1, t + 1);
            asm volatile("s_waitcnt vmcnt(8)" ::: "memory");
        } else {
            asm volatile("s_waitcnt vmcnt(0)" ::: "memory");
        }
        __builtin_amdgcn_s_barrier();
        __builtin_amdgcn_sched_barrier(0);

        const us* KT = KT_(mh, t & 1);
        const us* VT = VT_(mh, t & 1);
        const int m0 = mh * 1024 + t * 64;
        const bool skip = (m0 + 63 < lo_min) || (m0 > hi_max);
        const bool full = (m0 >= lo_max) && (m0 + 63 <= hi_min);

        __builtin_amdgcn_s_setprio(1);
        #pragma unroll
        for (int mss = 0; mss < 2; ++mss) {
            const int row = mss * 32 + ln;
            const int rs = row & 7;
            short8 a0 = *(const short8*)&KT[row * 64 + (((0 + hi) ^ rs) << 3)];
            short8 a1 = *(const short8*)&KT[row * 64 + (((2 + hi) ^ rs) << 3)];
            short8 a2 = *(const short8*)&KT[row * 64 + (((4 + hi) ^ rs) << 3)];
            short8 a3 = *(const short8*)&KT[row * 64 + (((6 + hi) ^ rs) << 3)];
            f32x16 st = __builtin_amdgcn_mfma_f32_32x32x16_bf16(a0, qf0, Z, 0, 0, 0);
            st = __builtin_amdgcn_mfma_f32_32x32x16_bf16(a1, qf1, st, 0, 0, 0);
            st = __builtin_amdgcn_mfma_f32_32x32x16_bf16(a2, qf2, st, 0, 0, 0);
            st = __builtin_amdgcn_mfma_f32_32x32x16_bf16(a3, qf3, st, 0, 0, 0);

            float p[16];
            #pragma unroll
            for (int r = 0; r < 16; ++r) {
                p[r] = __builtin_amdgcn_exp2f(st[r]);  // no max-subtraction: |logit| small
                Lp += p[r];
            }
            if (skip) continue;
            if (!full) {
                #pragma unroll
                for (int r = 0; r < 16; ++r) {
                    const int mg = m0 + mss * 32 + (r & 3) + 8 * (r >> 2) + 4 * hi;
                    if (mg < lo_n || mg > hi_n) p[r] = 0.f;
                }
            }
            #pragma unroll
            for (int c16 = 0; c16 < 2; ++c16) {
                uint4v pw;
                pw[0] = cvtpk(p[c16 * 8 + 0], p[c16 * 8 + 1]);
                pw[1] = cvtpk(p[c16 * 8 + 2], p[c16 * 8 + 3]);
                pw[2] = cvtpk(p[c16 * 8 + 4], p[c16 * 8 + 5]);
                pw[3] = cvtpk(p[c16 * 8 + 6], p[c16 * 8 + 7]);
                short8 pb = __builtin_bit_cast(short8, pw);
                const int blkA = mss * 4 + c16 * 2;
                {
                    const int rv = ln, rvs = rv & 7;
                    short4v va  = *(const short4v*)&VT[rv * 64 + ((blkA ^ rvs) << 3) + hi * 4];
                    short4v vb2 = *(const short4v*)&VT[rv * 64 + (((blkA + 1) ^ rvs) << 3) + hi * 4];
                    O0 = __builtin_amdgcn_mfma_f32_32x32x16_bf16(comb(va, vb2), pb, O0, 0, 0, 0);
                }
                {
                    const int rv = 32 + ln, rvs = rv & 7;
                    short4v va  = *(const short4v*)&VT[rv * 64 + ((blkA ^ rvs) << 3) + hi * 4];
                    short4v vb2 = *(const short4v*)&VT[rv * 64 + (((blkA + 1) ^ rvs) << 3) + hi * 4];
                    O1 = __builtin_amdgcn_mfma_f32_32x32x16_bf16(comb(va, vb2), pb, O1, 0, 0, 0);
                }
            }
        }
        __builtin_amdgcn_s_setprio(0);
        __builtin_amdgcn_sched_barrier(0);
        __builtin_amdgcn_s_barrier();
    }

    // ---- in-block combine across 4 m-streams (L additive; no max-tracking) ----
    float Lw = Lp + __shfl_xor(Lp, 32);

    float* cO = (float*)lds_us;              // [6 slots][32 q][64 d] f32 = 48KB (K region)
    float* cL = (float*)(lds_us + 32768);    // [6][32] (V region)
    if (mh != 0) {
        const int slot = (mh - 1) * 2 + nh;
        float* dsto = cO + slot * 2048 + ln * 64;
        #pragma unroll
        for (int rq = 0; rq < 4; ++rq) {
            f32x4 s0, s1;
            #pragma unroll
            for (int j = 0; j < 4; ++j) { s0[j] = O0[rq * 4 + j]; s1[j] = O1[rq * 4 + j]; }
            *(f32x4*)&dsto[rq * 8 + hi * 4] = s0;
            *(f32x4*)&dsto[32 + rq * 8 + hi * 4] = s1;
        }
        if (hi == 0) cL[slot * 32 + ln] = Lw;
    }
    __syncthreads();
    if (mh != 0) return;

    float gL = Lw;
    #pragma unroll
    for (int i = 0; i < 3; ++i) gL += cL[(i * 2 + nh) * 32 + ln];
    const float rl2 = 1.0f / gL;

    f32x16 On0 = O0, On1 = O1;
    #pragma unroll
    for (int i = 0; i < 3; ++i) {
        const float* s = cO + (i * 2 + nh) * 2048 + ln * 64;
        #pragma unroll
        for (int rq = 0; rq < 4; ++rq) {
            f32x4 a = *(const f32x4*)&s[rq * 8 + hi * 4];
            f32x4 c = *(const f32x4*)&s[32 + rq * 8 + hi * 4];
            #pragma unroll
            for (int j = 0; j < 4; ++j) { On0[rq * 4 + j] += a[j]; On1[rq * 4 + j] += c[j]; }
        }
    }
    #pragma unroll
    for (int i = 0; i < 16; ++i) { On0[i] *= rl2; On1[i] *= rl2; }

    // ---- fused epilogue: out = Wo . [o; x] + bo  (32x32 MFMAs) ----
    short8 Bf[8];
    {
        uint4v w0, w1, w2, w3;
        w0[0] = cvtpk(On0[0], On0[1]);   w0[1] = cvtpk(On0[2], On0[3]);
        w0[2] = cvtpk(On0[4], On0[5]);   w0[3] = cvtpk(On0[6], On0[7]);
        w1[0] = cvtpk(On0[8], On0[9]);   w1[1] = cvtpk(On0[10], On0[11]);
        w1[2] = cvtpk(On0[12], On0[13]); w1[3] = cvtpk(On0[14], On0[15]);
        w2[0] = cvtpk(On1[0], On1[1]);   w2[1] = cvtpk(On1[2], On1[3]);
        w2[2] = cvtpk(On1[4], On1[5]);   w2[3] = cvtpk(On1[6], On1[7]);
        w3[0] = cvtpk(On1[8], On1[9]);   w3[1] = cvtpk(On1[10], On1[11]);
        w3[2] = cvtpk(On1[12], On1[13]); w3[3] = cvtpk(On1[14], On1[15]);
        Bf[0] = __builtin_bit_cast(short8, w0);
        Bf[1] = __builtin_bit_cast(short8, w1);
        Bf[2] = __builtin_bit_cast(short8, w2);
        Bf[3] = __builtin_bit_cast(short8, w3);
    }
    const us* xrow = Xbt + (size_t)(b * NN + n032 + ln) * ND;
    #pragma unroll
    for (int c4 = 0; c4 < 4; ++c4)
        Bf[4 + c4] = comb(*(const short4v*)(xrow + c4 * 16 + hi * 4),
                          *(const short4v*)(xrow + c4 * 16 + hi * 4 + 8));

    f32x16 acc0, acc1;
    #pragma unroll
    for (int rq = 0; rq < 4; ++rq) {
        f32x4 b0 = *(const f32x4*)&bo[rq * 8 + hi * 4];
        f32x4 b1 = *(const f32x4*)&bo[32 + rq * 8 + hi * 4];
        #pragma unroll
        for (int j = 0; j < 4; ++j) { acc0[rq * 4 + j] = b0[j]; acc1[rq * 4 + j] = b1[j]; }
    }
    const us* wr0 = Wob + (size_t)ln * 128;
    const us* wr1 = Wob + (size_t)(32 + ln) * 128;
    #pragma unroll
    for (int kc = 0; kc < 8; ++kc) {
        short8 wf0 = comb(*(const short4v*)(wr0 + kc * 16 + hi * 4),
                          *(const short4v*)(wr0 + kc * 16 + hi * 4 + 8));
        short8 wf1 = comb(*(const short4v*)(wr1 + kc * 16 + hi * 4),
                          *(const short4v*)(wr1 + kc * 16 + hi * 4 + 8));
        acc0 = __builtin_amdgcn_mfma_f32_32x32x16_bf16(wf0, Bf[kc], acc0, 0, 0, 0);
        acc1 = __builtin_amdgcn_mfma_f32_32x32x16_bf16(wf1, Bf[kc], acc1, 0, 0, 0);
    }
    #pragma unroll
    for (int r = 0; r < 16; ++r) {
        const int od = (r & 3) + 8 * (r >> 2) + 4 * hi;
        out[((size_t)b * 64 + od) * NN + n032 + ln] = acc0[r];
        out[((size_t)b * 64 + 32 + od) * NN + n032 + ln] = acc1[r];
    }
}

extern "C" void kernel_launch(void* const* d_in, const int* in_sizes, int n_in,
                              void* d_out, int out_size, void* d_ws, size_t ws_size,
                              hipStream_t stream) {
    (void)in_sizes; (void)n_in; (void)out_size; (void)ws_size;
    const float* x  = (const float*)d_in[0];
    const float* Wq = (const float*)d_in[1];
    const float* bq = (const float*)d_in[2];
    const float* Wk = (const float*)d_in[3];
    const float* bk = (const float*)d_in[4];
    const float* Wv = (const float*)d_in[5];
    const float* bv = (const float*)d_in[6];
    const float* Wo = (const float*)d_in[7];
    const float* bo = (const float*)d_in[8];
    const int* ord  = (const int*)d_in[9];
    float* out = (float*)d_out;

    // workspace: 4 x 2MB bf16 + 16KB = 8.02MB (proven footprint)
    us* Qt  = (us*)d_ws;
    us* Kt  = Qt  + (size_t)NB * NN * ND;
    us* Vm  = Kt  + (size_t)NB * NN * ND;
    us* Xbt = Vm  + (size_t)NB * NN * ND;
    us* Wob = Xbt + (size_t)NB * NN * ND;

    hipFuncSetAttribute(reinterpret_cast<const void*>(attn_kernel),
                        hipFuncAttributeMaxDynamicSharedMemorySize, 131072);

    cvt_wo_kernel<<<dim3(32), dim3(256), 0, stream>>>(Wo, Wob);
    proj_kernel<<<dim3(NB * 64 * 2), dim3(256), 0, stream>>>(
        x, Wq, bq, Wk, bk, Wv, bv, Qt, Kt, Vm, Xbt);
    attn_kernel<<<dim3(256), dim3(512), 131072, stream>>>(
        Qt, Kt, Vm, Xbt, Wob, bo, ord, out);
}